// Round 17
// baseline (61.803 us; speedup 1.0000x reference)
//
#include <hip/hip_runtime.h>
#include <math.h>

#define NBC   16          // b*2
#define NF    160
#define NT    1000
#define TS    64          // sites per block

typedef __attribute__((ext_vector_type(8))) short short8;
typedef __attribute__((ext_vector_type(4))) float f32x4;

static __device__ __forceinline__ short f2bf(float x) {
    unsigned u = __builtin_bit_cast(unsigned, x);
    unsigned r = (u + 0x7fffu + ((u >> 16) & 1u)) >> 16;
    return (short)r;
}
static __device__ __forceinline__ float bf2f(short s) {
    unsigned u = ((unsigned)(unsigned short)s) << 16;
    return __builtin_bit_cast(float, u);
}

// ---------------------------------------------------------------------------
// k13 v8: ALL-MFMA formulation, P2 B-operands now SPLIT hi/lo (v7's hi-only
// staging lost 2^-8 per term against inv<=316-magnitude cancellation -> absmax
// 64). 640 thr (10 waves), TS=64, grid (16,16).
//  P1: Q = LN(qlw @ far)·σ  (5-chunk streamed MFMA, split-bf16)
//  cs: colsum of Q over f
//  P2: 3 GEMMs A_m = Q^T @ {m0·inv, m1·inv, inv} via MFMA, BOTH operands
//      split hi/lo (3-MFMA scheme, 2^-16 effective)
//  EP: s[q][j] = G_j(α_j A0 + β_j A1 + γ_j A2)[ts+q][ts] + H_j·cs[ts+q]
// ---------------------------------------------------------------------------
__global__ __launch_bounds__(640) void k13_fused(const float* __restrict__ far,
                                                 const float* __restrict__ mix,
                                                 const float* __restrict__ qlw,
                                                 const float* __restrict__ qlb,
                                                 const float* __restrict__ qng,
                                                 const float* __restrict__ qnb,
                                                 const float* __restrict__ qvec,
                                                 const float* __restrict__ kcw,
                                                 const float* __restrict__ kcb,
                                                 const float* __restrict__ klw,
                                                 const float* __restrict__ klb,
                                                 const float* __restrict__ kng,
                                                 const float* __restrict__ knb,
                                                 const float* __restrict__ kvec,
                                                 float* __restrict__ W) {
    __shared__ float pool[19104];            // 76.4 KB
    __shared__ float lnM[80], lnI[80], cs[80];
    __shared__ float psum[400];
    float* Qlds = pool;                          // [160][81] = 12960 fl
    float* redS = pool;                          // alias (pre-Qlds)
    float* redQ = pool + 3280;
    short* fBhi = (short*)(pool + 12960);        // 2560 sh (P1 far frags)
    short* fBlo = fBhi + 2560;
    short* MBhi = (short*)(pool + 12960);        // 6144 sh (P2 M frags hi)
    short* MBlo = MBhi + 6144;                   // 6144 sh (P2 M frags lo)
    float* Dbuf = pool;                          // [3][80][66] = 15840 fl (EP)

    const int bc = blockIdx.x;
    const int t0 = blockIdx.y * TS;
    const int tid = threadIdx.x;
    const int w = __builtin_amdgcn_readfirstlane(tid >> 6);  // 0..9
    const int l = tid & 63;
    const int b = bc >> 1, c = bc & 1;
    const float sgn = c ? -1.f : 1.f;
    const float* Xb = far + (size_t)bc * NF * NT;
    const int row = l & 15;
    const int kb = l >> 4;

    // ---- A fragments for P1 (qlw rows 16w..16w+15), hi/lo bf16 ----
    short8 Ahi[5], Alo[5];
    #pragma unroll
    for (int fc = 0; fc < 5; ++fc) {
        const float* ap = qlw + (size_t)(16 * w + row) * NF + fc * 32 + kb * 8;
        float4 x0 = *(const float4*)(ap + 0);
        float4 x1 = *(const float4*)(ap + 4);
        float xv[8] = {x0.x, x0.y, x0.z, x0.w, x1.x, x1.y, x1.z, x1.w};
        short8 h, lo;
        #pragma unroll
        for (int j = 0; j < 8; ++j) {
            short hj = f2bf(xv[j]);
            h[j] = hj;
            lo[j] = f2bf(xv[j] - bf2f(hj));
        }
        Ahi[fc] = h; Alo[fc] = lo;
    }

    // ---- P1: streamed MFMA over 5 f-chunks ----
    f32x4 qa0 = {0.f, 0.f, 0.f, 0.f}, qa1 = qa0, qa2 = qa0, qa3 = qa0, qa4 = qa0;
    #pragma unroll
    for (int fc = 0; fc < 5; ++fc) {
        #pragma unroll
        for (int i = 0; i < 4; ++i) {
            int e = tid + i * 640;           // 0..2559
            int fi_l = e / 80, j = e - fi_l * 80;
            int tq = t0 - 3 + j;
            int fi = fc * 32 + fi_l;
            float v = (tq >= 0 && tq < NT) ? Xb[(size_t)fi * NT + tq] * sgn : 0.f;
            short hi = f2bf(v);
            int tt = j >> 4;
            int sl = ((fi_l >> 3) << 4) | (j & 15);
            int idx = (tt * 64 + sl) * 8 + (fi_l & 7);
            fBhi[idx] = hi;
            fBlo[idx] = f2bf(v - bf2f(hi));
        }
        __syncthreads();
        #pragma unroll
        for (int tt = 0; tt < 5; ++tt) {
            short8 bh = *(const short8*)&fBhi[(tt * 64 + l) * 8];
            short8 bl = *(const short8*)&fBlo[(tt * 64 + l) * 8];
            f32x4 a = (tt == 0) ? qa0 : (tt == 1) ? qa1 : (tt == 2) ? qa2 : (tt == 3) ? qa3 : qa4;
            a = __builtin_amdgcn_mfma_f32_16x16x32_bf16(Ahi[fc], bh, a, 0, 0, 0);
            a = __builtin_amdgcn_mfma_f32_16x16x32_bf16(Ahi[fc], bl, a, 0, 0, 0);
            a = __builtin_amdgcn_mfma_f32_16x16x32_bf16(Alo[fc], bh, a, 0, 0, 0);
            if (tt == 0) qa0 = a; else if (tt == 1) qa1 = a; else if (tt == 2) qa2 = a;
            else if (tt == 3) qa3 = a; else qa4 = a;
        }
        __syncthreads();
    }

    // ---- LN stats ----
    float qlbv[4], gam[4], bet[4];
    #pragma unroll
    for (int r = 0; r < 4; ++r) {
        int fo = 16 * w + kb * 4 + r;
        qlbv[r] = qlb[fo];
        float sq = 1.f / (1.f + expf(-qvec[fo]));
        gam[r] = qng[fo] * sq;
        bet[r] = qnb[fo] * sq;
    }
    #pragma unroll
    for (int tt = 0; tt < 5; ++tt) {
        f32x4 a = (tt == 0) ? qa0 : (tt == 1) ? qa1 : (tt == 2) ? qa2 : (tt == 3) ? qa3 : qa4;
        float v0 = a[0] + qlbv[0], v1 = a[1] + qlbv[1];
        float v2 = a[2] + qlbv[2], v3 = a[3] + qlbv[3];
        int j = tt * 16 + row;
        redS[j * 41 + w * 4 + kb] = v0 + v1 + v2 + v3;
        redQ[j * 41 + w * 4 + kb] = v0 * v0 + v1 * v1 + v2 * v2 + v3 * v3;
    }
    __syncthreads();

    if (tid < 80) {
        float s = 0.f, q = 0.f;
        #pragma unroll 8
        for (int j = 0; j < 40; ++j) {
            s += redS[tid * 41 + j];
            q += redQ[tid * 41 + j];
        }
        float mean = s * (1.f / NF);
        float var = q * (1.f / NF) - mean * mean;
        lnM[tid] = mean;
        lnI[tid] = 1.f / sqrtf(var + 1e-5f);
    }
    __syncthreads();

    #pragma unroll
    for (int tt = 0; tt < 5; ++tt) {
        f32x4 a = (tt == 0) ? qa0 : (tt == 1) ? qa1 : (tt == 2) ? qa2 : (tt == 3) ? qa3 : qa4;
        int j = tt * 16 + row;
        float mean = lnM[j], inv = lnI[j];
        #pragma unroll
        for (int r = 0; r < 4; ++r) {
            int fo = 16 * w + kb * 4 + r;
            float v = a[r] + qlbv[r];
            Qlds[fo * 81 + j] = (v - mean) * inv * gam[r] + bet[r];
        }
    }
    __syncthreads();

    // ---- colsum cs[j] = sum_f Q[f][j] ----
    if (tid < 400) {
        int u = tid / 5, ch = tid - (tid / 5) * 5;
        float s = 0.f;
        #pragma unroll 8
        for (int f = ch * 32; f < ch * 32 + 32; ++f) s += Qlds[f * 81 + u];
        psum[tid] = s;
    }
    __syncthreads();
    if (tid < 80)
        cs[tid] = psum[tid * 5] + psum[tid * 5 + 1] + psum[tid * 5 + 2]
                + psum[tid * 5 + 3] + psum[tid * 5 + 4];
    __syncthreads();

    // ---- folded key constants ----
    float alpha[4], beta4[4], gamm[4], G[4], H[4];
    {
        float M0[4], M1[4], B4[4];
        #pragma unroll
        for (int jo = 0; jo < 4; ++jo) {
            float m0 = 0.f, m1 = 0.f, bb = klb[jo];
            #pragma unroll
            for (int ji = 0; ji < 4; ++ji) {
                float kl = klw[jo * 4 + ji];
                m0 = fmaf(kl, kcw[(4 * c + ji) * 2 + 0], m0);
                m1 = fmaf(kl, kcw[(4 * c + ji) * 2 + 1], m1);
                bb = fmaf(kl, kcb[4 * c + ji], bb);
            }
            M0[jo] = m0; M1[jo] = m1; B4[jo] = bb;
        }
        float am = 0.25f * (M0[0] + M0[1] + M0[2] + M0[3]);
        float bm = 0.25f * (M1[0] + M1[1] + M1[2] + M1[3]);
        float cm = 0.25f * (B4[0] + B4[1] + B4[2] + B4[3]);
        #pragma unroll
        for (int jo = 0; jo < 4; ++jo) {
            alpha[jo] = M0[jo] - am;
            beta4[jo] = M1[jo] - bm;
            gamm[jo]  = B4[jo] - cm;
            float sk = 0.5f / (1.f + expf(-kvec[jo]));
            G[jo] = kng[jo] * sk;
            H[jo] = knb[jo] * sk;
        }
    }

    // ---- P2: 3 GEMMs A_m = Q^T @ {m0*inv, m1*inv, inv}, split hi/lo B ----
    const float* mix0 = mix + (size_t)(b * 2) * NF * NT;
    const float* mix1 = mix0 + (size_t)NF * NT;
    const int ug = w % 5;           // u-subtile 0..4
    const int tgb = (w / 5) * 2;    // t-subtile base {0,2}

    f32x4 a00 = {0.f, 0.f, 0.f, 0.f}, a01 = a00;   // mat0, dt 0/1
    f32x4 a10 = a00, a11 = a00;                    // mat1
    f32x4 a20 = a00, a21 = a00;                    // mat2

    #pragma unroll
    for (int kc = 0; kc < 5; ++kc) {
        // stage M fragments (split hi/lo bf16)
        #pragma unroll
        for (int i = 0; i < 4; ++i) {
            int e = tid + i * 640;
            if (e < 2048) {
                int f_l = e >> 6, tl = e & 63;
                int t = t0 + tl;
                int f = kc * 32 + f_l;
                float m0 = 0.f, m1 = 0.f;
                bool vt = t < NT;
                if (vt) {
                    m0 = mix0[(size_t)f * NT + t];
                    m1 = mix1[(size_t)f * NT + t];
                }
                float d0 = fmaf(alpha[0], m0, fmaf(beta4[0], m1, gamm[0]));
                float d1 = fmaf(alpha[1], m0, fmaf(beta4[1], m1, gamm[1]));
                float d2 = fmaf(alpha[2], m0, fmaf(beta4[2], m1, gamm[2]));
                float d3 = fmaf(alpha[3], m0, fmaf(beta4[3], m1, gamm[3]));
                float var = 0.25f * (d0 * d0 + d1 * d1 + d2 * d2 + d3 * d3);
                float inv = vt ? (1.f / sqrtf(var + 1e-5f)) : 0.f;
                int tg = tl >> 4;
                int sl = ((f_l >> 3) << 4) | (tl & 15);
                int base = ((tg * 64 + sl) * 8) + (f_l & 7);
                float v0m = m0 * inv, v1m = m1 * inv;
                short h0 = f2bf(v0m), h1 = f2bf(v1m), h2 = f2bf(inv);
                MBhi[base]        = h0;
                MBhi[base + 2048] = h1;
                MBhi[base + 4096] = h2;
                MBlo[base]        = f2bf(v0m - bf2f(h0));
                MBlo[base + 2048] = f2bf(v1m - bf2f(h1));
                MBlo[base + 4096] = f2bf(inv - bf2f(h2));
            }
        }
        __syncthreads();
        // A-frag from Qlds (split hi/lo)
        short8 Ah, Al;
        #pragma unroll
        for (int jj = 0; jj < 8; ++jj) {
            int f = kc * 32 + kb * 8 + jj;
            float v = Qlds[f * 81 + ug * 16 + row];
            short hj = f2bf(v);
            Ah[jj] = hj;
            Al[jj] = f2bf(v - bf2f(hj));
        }
        // MFMA: 3 mats x 2 t-subtiles x 3 (AhBh, AhBl, AlBh)
        #pragma unroll
        for (int mat = 0; mat < 3; ++mat) {
            int s0 = (mat * 4 + tgb + 0) * 64 + l;
            int s1 = (mat * 4 + tgb + 1) * 64 + l;
            short8 bh0 = *(const short8*)&MBhi[s0 * 8];
            short8 bl0 = *(const short8*)&MBlo[s0 * 8];
            short8 bh1 = *(const short8*)&MBhi[s1 * 8];
            short8 bl1 = *(const short8*)&MBlo[s1 * 8];
            f32x4 a0 = (mat == 0) ? a00 : (mat == 1) ? a10 : a20;
            f32x4 a1 = (mat == 0) ? a01 : (mat == 1) ? a11 : a21;
            a0 = __builtin_amdgcn_mfma_f32_16x16x32_bf16(Ah, bh0, a0, 0, 0, 0);
            a0 = __builtin_amdgcn_mfma_f32_16x16x32_bf16(Ah, bl0, a0, 0, 0, 0);
            a0 = __builtin_amdgcn_mfma_f32_16x16x32_bf16(Al, bh0, a0, 0, 0, 0);
            a1 = __builtin_amdgcn_mfma_f32_16x16x32_bf16(Ah, bh1, a1, 0, 0, 0);
            a1 = __builtin_amdgcn_mfma_f32_16x16x32_bf16(Ah, bl1, a1, 0, 0, 0);
            a1 = __builtin_amdgcn_mfma_f32_16x16x32_bf16(Al, bh1, a1, 0, 0, 0);
            if (mat == 0) { a00 = a0; a01 = a1; }
            else if (mat == 1) { a10 = a0; a11 = a1; }
            else { a20 = a0; a21 = a1; }
        }
        __syncthreads();
    }

    // ---- write D subtiles: Dbuf[mat][u][t], stride 66 ----
    #pragma unroll
    for (int r = 0; r < 4; ++r) {
        int u = ug * 16 + kb * 4 + r;
        int tA = (tgb + 0) * 16 + row;
        int tB = (tgb + 1) * 16 + row;
        Dbuf[0 * 5280 + u * 66 + tA] = a00[r];
        Dbuf[0 * 5280 + u * 66 + tB] = a01[r];
        Dbuf[1 * 5280 + u * 66 + tA] = a10[r];
        Dbuf[1 * 5280 + u * 66 + tB] = a11[r];
        Dbuf[2 * 5280 + u * 66 + tA] = a20[r];
        Dbuf[2 * 5280 + u * 66 + tB] = a21[r];
    }
    __syncthreads();

    // ---- epilogue: scores + softmax -> W ----
    if (tid < 64) {
        int ts = tid;
        int t = t0 + ts;
        if (t < NT) {
            float* wp = W + ((size_t)bc * NT + t) * 16;
            #pragma unroll
            for (int q = 0; q < 4; ++q) {
                int j = ts + q;
                float csj = cs[j];
                float A0 = Dbuf[0 * 5280 + j * 66 + ts];
                float A1 = Dbuf[1 * 5280 + j * 66 + ts];
                float A2 = Dbuf[2 * 5280 + j * 66 + ts];
                float s0 = fmaf(G[0], fmaf(alpha[0], A0, fmaf(beta4[0], A1, gamm[0] * A2)), H[0] * csj);
                float s1 = fmaf(G[1], fmaf(alpha[1], A0, fmaf(beta4[1], A1, gamm[1] * A2)), H[1] * csj);
                float s2 = fmaf(G[2], fmaf(alpha[2], A0, fmaf(beta4[2], A1, gamm[2] * A2)), H[2] * csj);
                float s3 = fmaf(G[3], fmaf(alpha[3], A0, fmaf(beta4[3], A1, gamm[3] * A2)), H[3] * csj);
                float mx = fmaxf(fmaxf(s0, s1), fmaxf(s2, s3));
                float e0 = expf(s0 - mx), e1 = expf(s1 - mx);
                float e2 = expf(s2 - mx), e3 = expf(s3 - mx);
                float inv = 1.f / (e0 + e1 + e2 + e3);
                float4 v = {e0 * inv, e1 * inv, e2 * inv, e3 * inv};
                *(float4*)(wp + q * 4) = v;
            }
        }
    }
}

// ---------------------------------------------------------------------------
// complex 4x4 solve, partial pivoting (cabs1), fully unrolled
// ---------------------------------------------------------------------------
__device__ __forceinline__ void csolve4(float Ar[16], float Ai[16],
                                        float br[4], float bi[4],
                                        float wr[4], float wi[4]) {
    #pragma unroll
    for (int col = 0; col < 4; ++col) {
        #pragma unroll
        for (int r = col + 1; r < 4; ++r) {
            float cp = fabsf(Ar[col * 4 + col]) + fabsf(Ai[col * 4 + col]);
            float cr = fabsf(Ar[r * 4 + col]) + fabsf(Ai[r * 4 + col]);
            bool sw = cr > cp;
            #pragma unroll
            for (int m = col; m < 4; ++m) {
                float a0 = Ar[col * 4 + m], a1 = Ar[r * 4 + m];
                Ar[col * 4 + m] = sw ? a1 : a0;
                Ar[r * 4 + m]   = sw ? a0 : a1;
                float c0 = Ai[col * 4 + m], c1 = Ai[r * 4 + m];
                Ai[col * 4 + m] = sw ? c1 : c0;
                Ai[r * 4 + m]   = sw ? c0 : c1;
            }
            float b0 = br[col], b1 = br[r];
            br[col] = sw ? b1 : b0; br[r] = sw ? b0 : b1;
            float d0 = bi[col], d1 = bi[r];
            bi[col] = sw ? d1 : d0; bi[r] = sw ? d0 : d1;
        }
        float pr = Ar[col * 4 + col], pi = Ai[col * 4 + col];
        float den = 1.f / (pr * pr + pi * pi);
        #pragma unroll
        for (int r = col + 1; r < 4; ++r) {
            float nr = Ar[r * 4 + col], ni = Ai[r * 4 + col];
            float fr = (nr * pr + ni * pi) * den;
            float fi = (ni * pr - nr * pi) * den;
            #pragma unroll
            for (int m = col + 1; m < 4; ++m) {
                float tr = Ar[col * 4 + m], ti = Ai[col * 4 + m];
                Ar[r * 4 + m] -= fr * tr - fi * ti;
                Ai[r * 4 + m] -= fr * ti + fi * tr;
            }
            float tr = br[col], ti = bi[col];
            br[r] -= fr * tr - fi * ti;
            bi[r] -= fr * ti + fi * tr;
        }
    }
    #pragma unroll
    for (int col = 3; col >= 0; --col) {
        float sr = br[col], si = bi[col];
        #pragma unroll
        for (int m = col + 1; m < 4; ++m) {
            float tr = Ar[col * 4 + m], ti = Ai[col * 4 + m];
            sr -= tr * wr[m] - ti * wi[m];
            si -= tr * wi[m] + ti * wr[m];
        }
        float pr = Ar[col * 4 + col], pi = Ai[col * 4 + col];
        float den = 1.f / (pr * pr + pi * pi);
        wr[col] = (sr * pr + si * pi) * den;
        wi[col] = (si * pr - sr * pi) * den;
    }
}

// ---------------------------------------------------------------------------
// k4: per (b,f,t): build rank-1 value/out, assemble A,rhs, solve, Wiener sum
// ---------------------------------------------------------------------------
__global__ __launch_bounds__(256) void k4_final(const float* __restrict__ far,
                                                const float* __restrict__ mix,
                                                const float* __restrict__ Wt,
                                                const float* __restrict__ vvec,
                                                float* __restrict__ out) {
    const int t = blockIdx.x * 256 + threadIdx.x;
    const int f = blockIdx.y;
    const int b = blockIdx.z;
    if (t >= NT) return;

    const float* fr  = far + (size_t)(b * 2 + 0) * NF * NT + (size_t)f * NT;
    const float* fim = far + (size_t)(b * 2 + 1) * NF * NT + (size_t)f * NT;
    float ur[4], ui[4];
    #pragma unroll
    for (int d = 0; d < 4; ++d) {
        int tp = t - 3 + d;
        bool ok = tp >= 0;
        ur[d] = ok ? fr[tp] : 0.f;
        ui[d] = ok ? fim[tp] : 0.f;
    }
    float m0 = mix[(size_t)(b * 2 + 0) * NF * NT + (size_t)f * NT + t];
    float m1 = mix[(size_t)(b * 2 + 1) * NF * NT + (size_t)f * NT + t];

    float sv[4];
    #pragma unroll
    for (int i = 0; i < 4; ++i) sv[i] = 1.f / (1.f + expf(-vvec[i]));

    const float* w0p = Wt + ((size_t)(b * 2 + 0) * NT + t) * 16;
    const float* w1p = Wt + ((size_t)(b * 2 + 1) * NT + t) * 16;

    float g0[4], g1[4];
    #pragma unroll
    for (int j = 0; j < 4; ++j) { g0[j] = 0.f; g1[j] = 0.f; }
    #pragma unroll
    for (int i = 0; i < 4; ++i) {
        float a0 = ur[i] * sv[i];
        float a1 = -ui[i] * sv[i];
        #pragma unroll
        for (int j = 0; j < 4; ++j) {
            g0[j] = fmaf(a0, w0p[i * 4 + j], g0[j]);
            g1[j] = fmaf(a1, w1p[i * 4 + j], g1[j]);
        }
    }

    float Ar[16], Ai[16], br[4], bi[4], wr[4], wi[4];
    #pragma unroll
    for (int j = 0; j < 4; ++j) {
        #pragma unroll
        for (int m = 0; m < 4; ++m) {
            float e = (j == m) ? (1.0f + 1e-8f) : 1e-8f;
            Ar[j * 4 + m] = fmaf(ur[m], g0[j], e);
            Ai[j * 4 + m] = fmaf(-ui[m], g1[j], e);
        }
        br[j] = m0 * g0[j];
        bi[j] = m1 * g1[j];
    }

    csolve4(Ar, Ai, br, bi, wr, wi);

    float resr = 0.f, resi = 0.f;
    #pragma unroll
    for (int d = 0; d < 4; ++d) {
        resr += ur[d] * wr[d] - ui[d] * wi[d];
        resi += ur[d] * wi[d] + ui[d] * wr[d];
    }
    out[(size_t)(b * 2 + 0) * NF * NT + (size_t)f * NT + t] = resr;
    out[(size_t)(b * 2 + 1) * NF * NT + (size_t)f * NT + t] = resi;
}

// ---------------------------------------------------------------------------
extern "C" void kernel_launch(void* const* d_in, const int* in_sizes, int n_in,
                              void* d_out, int out_size, void* d_ws, size_t ws_size,
                              hipStream_t stream) {
    const float* far  = (const float*)d_in[0];
    const float* mix  = (const float*)d_in[1];
    const float* kcw  = (const float*)d_in[2];
    const float* kcb  = (const float*)d_in[3];
    const float* qlw  = (const float*)d_in[4];
    const float* qlb  = (const float*)d_in[5];
    const float* qng  = (const float*)d_in[6];
    const float* qnb  = (const float*)d_in[7];
    const float* klw  = (const float*)d_in[8];
    const float* klb  = (const float*)d_in[9];
    const float* kng  = (const float*)d_in[10];
    const float* knb  = (const float*)d_in[11];
    const float* qvec = (const float*)d_in[12];
    const float* kvec = (const float*)d_in[13];
    const float* vvec = (const float*)d_in[14];

    float* W = (float*)d_ws;                 // 16*1000*16 floats
    float* out = (float*)d_out;

    k13_fused<<<dim3(NBC, (NT + TS - 1) / TS), 640, 0, stream>>>(
        far, mix, qlw, qlb, qng, qnb, qvec, kcw, kcb, klw, klb, kng, knb, kvec, W);
    k4_final<<<dim3(4, NF, 8), 256, 0, stream>>>(far, mix, W, vvec, out);
}